// Round 3
// baseline (388.896 us; speedup 1.0000x reference)
//
#include <hip/hip_runtime.h>
#include <hip/hip_bf16.h>

// Problem constants
#define B_   8
#define LQ   1024
#define LK   8192
#define D_   256
#define DC   128
#define EPSF 1e-6f

typedef __attribute__((ext_vector_type(8))) short short8;   // 8 bf16 (4 VGPRs)
typedef __attribute__((ext_vector_type(4))) float floatx4;  // 4 fp32 acc

static __device__ __forceinline__ floatx4 mfma16(short8 a, short8 b, floatx4 c) {
    return __builtin_amdgcn_mfma_f32_16x16x32_bf16(a, b, c, 0, 0, 0);
}
static __device__ __forceinline__ float fast_rcp(float x)  { return __builtin_amdgcn_rcpf(x); }
static __device__ __forceinline__ float fast_sqrt(float x) { return __builtin_amdgcn_sqrtf(x); }
static __device__ __forceinline__ float fast_ln(float x)   { return 0.69314718056f * __builtin_amdgcn_logf(x); }

// ---------------------------------------------------------------------------
// K1: G = W_up^T @ W_up  (128x128) bf16 row-major + Wt = W^T bf16 (128x256)
// into kc-buffer scratch. 512 threads / 4 d-quarters: dependent-load chain is
// 16 unroll-4 iterations (was 32) — halves the latency-exposed critical path.
__global__ __launch_bounds__(512) void k_G(const float* __restrict__ W,
                                           __hip_bfloat16* __restrict__ G,
                                           __hip_bfloat16* __restrict__ Wt) {
    __shared__ float red[512];
    int c1 = blockIdx.x;
    int t = threadIdx.x, c2 = t & 127, h = t >> 7;   // h = d-quarter 0..3
    int d0 = h * 64;
    float a0 = 0.f, a1 = 0.f, a2 = 0.f, a3 = 0.f;
#pragma unroll 4
    for (int d = 0; d < 64; d += 4) {
        a0 += W[(size_t)(d0 + d + 0) * DC + c1] * W[(size_t)(d0 + d + 0) * DC + c2];
        a1 += W[(size_t)(d0 + d + 1) * DC + c1] * W[(size_t)(d0 + d + 1) * DC + c2];
        a2 += W[(size_t)(d0 + d + 2) * DC + c1] * W[(size_t)(d0 + d + 2) * DC + c2];
        a3 += W[(size_t)(d0 + d + 3) * DC + c1] * W[(size_t)(d0 + d + 3) * DC + c2];
    }
    red[t] = (a0 + a1) + (a2 + a3);
    if (t < 256) Wt[(size_t)c1 * D_ + t] = __float2bfloat16(W[(size_t)t * DC + c1]);
    __syncthreads();
    if (h == 0)
        G[c1 * DC + c2] =
            __float2bfloat16(red[c2] + red[128 + c2] + red[256 + c2] + red[384 + c2]);
}

// ---------------------------------------------------------------------------
// K2: q_proj = (q @ W_up) -> bf16, q_sq fused. NOW 256 blocks x 32 rows
// (was 128 x 64 — half the GPU sat idle). Waves: wm = row-half (16 rows),
// wn = nt-half (4 of 8 column tiles).
__global__ __launch_bounds__(256) void k_qproj(const float* __restrict__ q,
                                               const __hip_bfloat16* __restrict__ Wt,
                                               __hip_bfloat16* __restrict__ qproj,
                                               float* __restrict__ q_sq) {
    __shared__ __hip_bfloat16 sA[32 * 72];   // q chunk (32 rows x 64 cols)
    __shared__ __hip_bfloat16 sB[128 * 72];  // W^T chunk: row=c, col=d_local
    int t = threadIdx.x, lane = t & 63, w = t >> 6;
    int quad = lane >> 4, li = lane & 15;
    int wm = w >> 1, wn = w & 1;
    int row0 = blockIdx.x * 32;

    float psum[2] = {0.f, 0.f};              // q_sq partial, row = it*16 + w*4 + quad
    floatx4 acc[4];
#pragma unroll
    for (int nt = 0; nt < 4; ++nt) acc[nt] = (floatx4){0.f, 0.f, 0.f, 0.f};

    for (int kc4 = 0; kc4 < 4; ++kc4) {
        // stage q chunk (fp32 -> bf16): 32 rows x 64 cols = 512 float4
#pragma unroll
        for (int it = 0; it < 2; ++it) {
            int idx = it * 256 + t;
            int r = idx >> 4, pos = idx & 15;
            float4 v = *(const float4*)(q + (size_t)(row0 + r) * D_ + kc4 * 64 + pos * 4);
            psum[it] += v.x * v.x + v.y * v.y + v.z * v.z + v.w * v.w;
            __hip_bfloat16* dst = &sA[r * 72 + pos * 4];
            dst[0] = __float2bfloat16(v.x); dst[1] = __float2bfloat16(v.y);
            dst[2] = __float2bfloat16(v.z); dst[3] = __float2bfloat16(v.w);
        }
        // stage Wt chunk: sB[c][dl] = Wt[c][kc4*64+dl], uint4 copies
#pragma unroll
        for (int it = 0; it < 4; ++it) {
            int e = it * 256 + t;          // [0,1024): 128 rows x 8 chunks
            int c = e >> 3, ch = e & 7;
            *(uint4*)&sB[c * 72 + ch * 8] =
                *(const uint4*)(Wt + (size_t)c * D_ + kc4 * 64 + ch * 8);
        }
        __syncthreads();
        short8 af[2];
#pragma unroll
        for (int ks = 0; ks < 2; ++ks)
            af[ks] = *(const short8*)&sA[(wm * 16 + li) * 72 + ks * 32 + quad * 8];
#pragma unroll
        for (int nt = 0; nt < 4; ++nt)
#pragma unroll
            for (int ks = 0; ks < 2; ++ks) {
                short8 bf = *(const short8*)&sB[((wn * 4 + nt) * 16 + li) * 72 + ks * 32 + quad * 8];
                acc[nt] = mfma16(af[ks], bf, acc[nt]);
            }
        __syncthreads();
    }
#pragma unroll
    for (int nt = 0; nt < 4; ++nt)
#pragma unroll
        for (int r = 0; r < 4; ++r) {
            int row = wm * 16 + quad * 4 + r;
            qproj[(size_t)(row0 + row) * DC + (wn * 4 + nt) * 16 + li] =
                __float2bfloat16(acc[nt][r]);
        }
#pragma unroll
    for (int it = 0; it < 2; ++it) {
        float s = psum[it];
        s += __shfl_xor(s, 1); s += __shfl_xor(s, 2);
        s += __shfl_xor(s, 4); s += __shfl_xor(s, 8);
        if (li == 0) q_sq[row0 + it * 16 + w * 4 + quad] = s;
    }
}

// ---------------------------------------------------------------------------
// K3 (fused dequant + k_sq): 1024 blocks x 64 rows. Unchanged from R2.
__global__ __launch_bounds__(256) void k_dq_ksq(const int* __restrict__ kq,
                                                const float* __restrict__ kscale,
                                                const float* __restrict__ kzero,
                                                const __hip_bfloat16* __restrict__ G,
                                                __hip_bfloat16* __restrict__ kc,
                                                float* __restrict__ k_sq) {
    __shared__ __hip_bfloat16 sK[64 * 132];   // 16.9 KB
    int t = threadIdx.x, lane = t & 63, w = t >> 6;
    int quad = lane >> 4, li = lane & 15;
    int b = blockIdx.x >> 7, l0 = (blockIdx.x & 127) * 64;

    const int4* codes = (const int4*)(kq + ((size_t)b * LK + l0) * DC);
    int col = (t & 31) * 4;
    float4 sc = *(const float4*)(kscale + b * DC + col);
    float4 zp = *(const float4*)(kzero + b * DC + col);
    __hip_bfloat16* kco = kc + ((size_t)b * LK + l0) * DC;
#pragma unroll
    for (int it = 0; it < 8; ++it) {
        int idx = it * 256 + t;            // [0,2048)
        int r = idx >> 5;
        int4 c4 = codes[idx];
        __hip_bfloat16 tmp[4];
        tmp[0] = __float2bfloat16(sc.x * ((float)c4.x - zp.x));
        tmp[1] = __float2bfloat16(sc.y * ((float)c4.y - zp.y));
        tmp[2] = __float2bfloat16(sc.z * ((float)c4.z - zp.z));
        tmp[3] = __float2bfloat16(sc.w * ((float)c4.w - zp.w));
        *(uint2*)&sK[r * 132 + col] = *(const uint2*)tmp;
        *(uint2*)(kco + idx * 4)    = *(const uint2*)tmp;
    }
    __syncthreads();

    short8 af[4];
#pragma unroll
    for (int ks = 0; ks < 4; ++ks)
        af[ks] = *(const short8*)&sK[(w * 16 + li) * 132 + ks * 32 + quad * 8];
    float s4[4] = {0.f, 0.f, 0.f, 0.f};
#pragma unroll
    for (int nt = 0; nt < 8; ++nt) {
        floatx4 a0 = (floatx4){0.f, 0.f, 0.f, 0.f};
#pragma unroll
        for (int ks = 0; ks < 4; ++ks) {
            short8 bf = *(const short8*)(G + (size_t)(nt * 16 + li) * DC + ks * 32 + quad * 8);
            a0 = mfma16(af[ks], bf, a0);
        }
        int c2 = nt * 16 + li;
#pragma unroll
        for (int r = 0; r < 4; ++r)
            s4[r] += a0[r] * __bfloat162float(sK[(w * 16 + quad * 4 + r) * 132 + c2]);
    }
#pragma unroll
    for (int r = 0; r < 4; ++r) {
        float v = s4[r];
        v += __shfl_xor(v, 1); v += __shfl_xor(v, 2);
        v += __shfl_xor(v, 4); v += __shfl_xor(v, 8);
        if (li == 0)
            k_sq[(size_t)b * LK + l0 + w * 16 + quad * 4 + r] = v;
    }
}

// ---------------------------------------------------------------------------
// K4: main. NEW: linear grid + XCD-locality mapping. b = bid & 7 pins each
// batch to one XCD (round-robin dispatch), whose working set kc[b] (2 MB) +
// qproj[b] (256 KB) fits the 4 MB per-XCD L2 -> all tile re-reads become L2
// hits; HBM is essentially write-only. m varies fastest so each kc n-tile is
// reused 8x back-to-back. Epilogue: LDS-transpose + coalesced nt stores (R2).
__global__ __launch_bounds__(256) void k_main(const __hip_bfloat16* __restrict__ qproj,
                                              const __hip_bfloat16* __restrict__ kc,
                                              const float* __restrict__ q_sq,
                                              const float* __restrict__ k_sq,
                                              float* __restrict__ out) {
    __shared__ __align__(16) char smem[128 * 72 * 2 * 2];   // 36,864 B union
    __hip_bfloat16* sA = (__hip_bfloat16*)smem;             // [128][72]
    __hip_bfloat16* sB = sA + 128 * 72;                     // [128][72]
    float* sO = (float*)smem;                               // [128][68] (34.8 KB)

    int t = threadIdx.x, lane = t & 63, w = t >> 6;
    int quad = lane >> 4, li = lane & 15;
    int wm = w >> 1, wn = w & 1;
    int bid = blockIdx.x;
    int b   = bid & 7;                 // XCD-pinned batch
    int rem = bid >> 3;                // 0..511
    int m0  = (rem & 7) << 7;          // m fastest within XCD
    int n0  = (rem >> 3) << 7;         // n slow: kc tile reused 8x in a row
    const uint4* Ag = (const uint4*)(qproj + ((size_t)b * LQ + m0) * DC);  // 16 u4/row
    const uint4* Bg = (const uint4*)(kc   + ((size_t)b * LK + n0) * DC);
    uint4* dA = (uint4*)sA; uint4* dB = (uint4*)sB;

    floatx4 acc[4][4];   // [i: m-frag][j: n-frag]; reg r = n-local (quad*4+r)
#pragma unroll
    for (int i = 0; i < 4; ++i)
#pragma unroll
        for (int j = 0; j < 4; ++j)
            acc[i][j] = (floatx4){0.f, 0.f, 0.f, 0.f};

    int r_ = t >> 3, ch_ = t & 7;          // 32 rows x 8 chunks per 256-thread pass
    // ---- load half 0 ----
    uint4 ra[4], rb[4];
#pragma unroll
    for (int it = 0; it < 4; ++it) {
        ra[it] = Ag[(it * 32 + r_) * 16 + ch_];
        rb[it] = Bg[(it * 32 + r_) * 16 + ch_];
    }
#pragma unroll
    for (int it = 0; it < 4; ++it) {
        dA[(it * 32 + r_) * 9 + ch_] = ra[it];
        dB[(it * 32 + r_) * 9 + ch_] = rb[it];
    }
    __syncthreads();
    // ---- prefetch half 1 while computing half 0 ----
#pragma unroll
    for (int it = 0; it < 4; ++it) {
        ra[it] = Ag[(it * 32 + r_) * 16 + 8 + ch_];
        rb[it] = Bg[(it * 32 + r_) * 16 + 8 + ch_];
    }
#pragma unroll
    for (int ks = 0; ks < 2; ++ks) {
        short8 qf[4], kf[4];
#pragma unroll
        for (int i = 0; i < 4; ++i) {
            qf[i] = *(const short8*)&sA[(wm * 64 + i * 16 + li) * 72 + ks * 32 + quad * 8];
            kf[i] = *(const short8*)&sB[(wn * 64 + i * 16 + li) * 72 + ks * 32 + quad * 8];
        }
#pragma unroll
        for (int i = 0; i < 4; ++i)
#pragma unroll
            for (int j = 0; j < 4; ++j)
                acc[i][j] = mfma16(kf[j], qf[i], acc[i][j]);   // A=kc, B=qproj
    }
    __syncthreads();
#pragma unroll
    for (int it = 0; it < 4; ++it) {
        dA[(it * 32 + r_) * 9 + ch_] = ra[it];
        dB[(it * 32 + r_) * 9 + ch_] = rb[it];
    }
    __syncthreads();
#pragma unroll
    for (int ks = 0; ks < 2; ++ks) {
        short8 qf[4], kf[4];
#pragma unroll
        for (int i = 0; i < 4; ++i) {
            qf[i] = *(const short8*)&sA[(wm * 64 + i * 16 + li) * 72 + ks * 32 + quad * 8];
            kf[i] = *(const short8*)&sB[(wn * 64 + i * 16 + li) * 72 + ks * 32 + quad * 8];
        }
#pragma unroll
        for (int i = 0; i < 4; ++i)
#pragma unroll
            for (int j = 0; j < 4; ++j)
                acc[i][j] = mfma16(kf[j], qf[i], acc[i][j]);
    }

    // ---- epilogue: LDS transpose + math + coalesced nontemporal stores ----
    int orow_t = t >> 4;            // 0..15
    int ocol4  = (t & 15) * 4;      // 0..60, multiple of 4
    float qsA[8], omqA[8];
#pragma unroll
    for (int qq = 0; qq < 8; ++qq) {
        qsA[qq]  = q_sq[(size_t)b * LQ + m0 + qq * 16 + orow_t];
        omqA[qq] = 1.f - fminf(qsA[qq], 1.f - EPSF);
    }
#pragma unroll
    for (int p = 0; p < 2; ++p) {
        __syncthreads();   // p=0: staging reads done; p=1: phase-0 reads done
#pragma unroll
        for (int jj = 0; jj < 2; ++jj) {
            int c = wn * 32 + jj * 16 + quad * 4;
#pragma unroll
            for (int i = 0; i < 4; ++i) {
                int m = wm * 64 + i * 16 + li;
                *(floatx4*)&sO[m * 68 + c] = acc[i][p * 2 + jj];
            }
        }
        __syncthreads();
        int nbase = (ocol4 >> 5) * 64 + p * 32 + (ocol4 & 31);
        floatx4 ks4 = *(const floatx4*)(k_sq + (size_t)b * LK + n0 + nbase);
        floatx4 kn;
#pragma unroll
        for (int r = 0; r < 4; ++r)
            kn[r] = 1.f - fminf(ks4[r], 1.f - EPSF);
#pragma unroll
        for (int qq = 0; qq < 8; ++qq) {
            int row = qq * 16 + orow_t;
            floatx4 v = *(const floatx4*)&sO[row * 68 + ocol4];
            float qs = qsA[qq], omq = omqA[qq];
            floatx4 o;
#pragma unroll
            for (int r = 0; r < 4; ++r) {
                float diff  = fmaxf(qs + ks4[r] - 2.f * v[r], 0.f);
                float delta = 2.f * diff * fast_rcp(omq * kn[r] + EPSF);
                float sq    = fast_sqrt(delta * (delta + 2.f));
                o[r] = fast_ln(1.f + delta + sq);
            }
            __builtin_nontemporal_store(
                o, (floatx4*)(out + ((size_t)b * LQ + m0 + row) * (size_t)LK + n0 + nbase));
        }
    }
}

// ---------------------------------------------------------------------------
extern "C" void kernel_launch(void* const* d_in, const int* in_sizes, int n_in,
                              void* d_out, int out_size, void* d_ws, size_t ws_size,
                              hipStream_t stream) {
    const float* q      = (const float*)d_in[0];
    const int*   kq     = (const int*)d_in[1];
    const float* kscale = (const float*)d_in[2];
    const float* kzero  = (const float*)d_in[3];
    const float* W      = (const float*)d_in[4];
    float* out = (float*)d_out;

    // workspace layout (19.2 MB total, unchanged)
    char* ws = (char*)d_ws;
    __hip_bfloat16* qproj = (__hip_bfloat16*)(ws);                 // 2,097,152 B
    __hip_bfloat16* kc    = (__hip_bfloat16*)(ws + 2097152);       // 16,777,216 B
    __hip_bfloat16* G     = (__hip_bfloat16*)(ws + 18874368);      //    32,768 B
    float*          q_sq  = (float*)(ws + 18907136);               //    32,768 B
    float*          k_sq  = (float*)(ws + 18939904);               //   262,144 B
    // Wt (bf16, 128x256 = 64 KB) aliases the START of kc: written by k_G,
    // read by k_qproj, then overwritten by k_dq_ksq (stream-ordered).
    __hip_bfloat16* Wt    = kc;

    k_G     <<<128, 512, 0, stream>>>(W, G, Wt);
    k_qproj <<<256, 256, 0, stream>>>(q, Wt, qproj, q_sq);
    k_dq_ksq<<<1024, 256, 0, stream>>>(kq, kscale, kzero, G, kc, k_sq);
    k_main  <<<4096, 256, 0, stream>>>(qproj, kc, q_sq, k_sq, out);
}

// Round 4
// 357.070 us; speedup vs baseline: 1.0891x; 1.0891x over previous
//
#include <hip/hip_runtime.h>
#include <hip/hip_bf16.h>

// Problem constants
#define B_   8
#define LQ   1024
#define LK   8192
#define D_   256
#define DC   128
#define EPSF 1e-6f

typedef __attribute__((ext_vector_type(8))) short short8;   // 8 bf16 (4 VGPRs)
typedef __attribute__((ext_vector_type(4))) float floatx4;  // 4 fp32 acc

static __device__ __forceinline__ floatx4 mfma16(short8 a, short8 b, floatx4 c) {
    return __builtin_amdgcn_mfma_f32_16x16x32_bf16(a, b, c, 0, 0, 0);
}
static __device__ __forceinline__ float fast_rcp(float x)  { return __builtin_amdgcn_rcpf(x); }
static __device__ __forceinline__ float fast_sqrt(float x) { return __builtin_amdgcn_sqrtf(x); }
static __device__ __forceinline__ float fast_ln(float x)   { return 0.69314718056f * __builtin_amdgcn_logf(x); }

// async global->LDS, 16 B per lane; LDS dest = wave-uniform base + lane*16
static __device__ __forceinline__ void gl16(const void* g, void* l) {
    __builtin_amdgcn_global_load_lds(
        (const __attribute__((address_space(1))) unsigned int*)g,
        (__attribute__((address_space(3))) unsigned int*)l, 16, 0, 0);
}

// ---------------------------------------------------------------------------
// K1: G = W_up^T @ W_up  (128x128) bf16 row-major + Wt = W^T bf16 (128x256)
// into kc-buffer scratch. (Unchanged from R3.)
__global__ __launch_bounds__(512) void k_G(const float* __restrict__ W,
                                           __hip_bfloat16* __restrict__ G,
                                           __hip_bfloat16* __restrict__ Wt) {
    __shared__ float red[512];
    int c1 = blockIdx.x;
    int t = threadIdx.x, c2 = t & 127, h = t >> 7;   // h = d-quarter 0..3
    int d0 = h * 64;
    float a0 = 0.f, a1 = 0.f, a2 = 0.f, a3 = 0.f;
#pragma unroll 4
    for (int d = 0; d < 64; d += 4) {
        a0 += W[(size_t)(d0 + d + 0) * DC + c1] * W[(size_t)(d0 + d + 0) * DC + c2];
        a1 += W[(size_t)(d0 + d + 1) * DC + c1] * W[(size_t)(d0 + d + 1) * DC + c2];
        a2 += W[(size_t)(d0 + d + 2) * DC + c1] * W[(size_t)(d0 + d + 2) * DC + c2];
        a3 += W[(size_t)(d0 + d + 3) * DC + c1] * W[(size_t)(d0 + d + 3) * DC + c2];
    }
    red[t] = (a0 + a1) + (a2 + a3);
    if (t < 256) Wt[(size_t)c1 * D_ + t] = __float2bfloat16(W[(size_t)t * DC + c1]);
    __syncthreads();
    if (h == 0)
        G[c1 * DC + c2] =
            __float2bfloat16(red[c2] + red[128 + c2] + red[256 + c2] + red[384 + c2]);
}

// ---------------------------------------------------------------------------
// K2: q_proj = (q @ W_up) -> bf16, q_sq fused. 256 blocks x 32 rows.
// (Unchanged from R3.)
__global__ __launch_bounds__(256) void k_qproj(const float* __restrict__ q,
                                               const __hip_bfloat16* __restrict__ Wt,
                                               __hip_bfloat16* __restrict__ qproj,
                                               float* __restrict__ q_sq) {
    __shared__ __hip_bfloat16 sA[32 * 72];   // q chunk (32 rows x 64 cols)
    __shared__ __hip_bfloat16 sB[128 * 72];  // W^T chunk: row=c, col=d_local
    int t = threadIdx.x, lane = t & 63, w = t >> 6;
    int quad = lane >> 4, li = lane & 15;
    int wm = w >> 1, wn = w & 1;
    int row0 = blockIdx.x * 32;

    float psum[2] = {0.f, 0.f};
    floatx4 acc[4];
#pragma unroll
    for (int nt = 0; nt < 4; ++nt) acc[nt] = (floatx4){0.f, 0.f, 0.f, 0.f};

    for (int kc4 = 0; kc4 < 4; ++kc4) {
#pragma unroll
        for (int it = 0; it < 2; ++it) {
            int idx = it * 256 + t;
            int r = idx >> 4, pos = idx & 15;
            float4 v = *(const float4*)(q + (size_t)(row0 + r) * D_ + kc4 * 64 + pos * 4);
            psum[it] += v.x * v.x + v.y * v.y + v.z * v.z + v.w * v.w;
            __hip_bfloat16* dst = &sA[r * 72 + pos * 4];
            dst[0] = __float2bfloat16(v.x); dst[1] = __float2bfloat16(v.y);
            dst[2] = __float2bfloat16(v.z); dst[3] = __float2bfloat16(v.w);
        }
#pragma unroll
        for (int it = 0; it < 4; ++it) {
            int e = it * 256 + t;          // [0,1024): 128 rows x 8 chunks
            int c = e >> 3, ch = e & 7;
            *(uint4*)&sB[c * 72 + ch * 8] =
                *(const uint4*)(Wt + (size_t)c * D_ + kc4 * 64 + ch * 8);
        }
        __syncthreads();
        short8 af[2];
#pragma unroll
        for (int ks = 0; ks < 2; ++ks)
            af[ks] = *(const short8*)&sA[(wm * 16 + li) * 72 + ks * 32 + quad * 8];
#pragma unroll
        for (int nt = 0; nt < 4; ++nt)
#pragma unroll
            for (int ks = 0; ks < 2; ++ks) {
                short8 bf = *(const short8*)&sB[((wn * 4 + nt) * 16 + li) * 72 + ks * 32 + quad * 8];
                acc[nt] = mfma16(af[ks], bf, acc[nt]);
            }
        __syncthreads();
    }
#pragma unroll
    for (int nt = 0; nt < 4; ++nt)
#pragma unroll
        for (int r = 0; r < 4; ++r) {
            int row = wm * 16 + quad * 4 + r;
            qproj[(size_t)(row0 + row) * DC + (wn * 4 + nt) * 16 + li] =
                __float2bfloat16(acc[nt][r]);
        }
#pragma unroll
    for (int it = 0; it < 2; ++it) {
        float s = psum[it];
        s += __shfl_xor(s, 1); s += __shfl_xor(s, 2);
        s += __shfl_xor(s, 4); s += __shfl_xor(s, 8);
        if (li == 0) q_sq[row0 + it * 16 + w * 4 + quad] = s;
    }
}

// ---------------------------------------------------------------------------
// K3 (fused dequant + k_sq): 1024 blocks x 64 rows. (Unchanged from R3.)
__global__ __launch_bounds__(256) void k_dq_ksq(const int* __restrict__ kq,
                                                const float* __restrict__ kscale,
                                                const float* __restrict__ kzero,
                                                const __hip_bfloat16* __restrict__ G,
                                                __hip_bfloat16* __restrict__ kc,
                                                float* __restrict__ k_sq) {
    __shared__ __hip_bfloat16 sK[64 * 132];   // 16.9 KB
    int t = threadIdx.x, lane = t & 63, w = t >> 6;
    int quad = lane >> 4, li = lane & 15;
    int b = blockIdx.x >> 7, l0 = (blockIdx.x & 127) * 64;

    const int4* codes = (const int4*)(kq + ((size_t)b * LK + l0) * DC);
    int col = (t & 31) * 4;
    float4 sc = *(const float4*)(kscale + b * DC + col);
    float4 zp = *(const float4*)(kzero + b * DC + col);
    __hip_bfloat16* kco = kc + ((size_t)b * LK + l0) * DC;
#pragma unroll
    for (int it = 0; it < 8; ++it) {
        int idx = it * 256 + t;            // [0,2048)
        int r = idx >> 5;
        int4 c4 = codes[idx];
        __hip_bfloat16 tmp[4];
        tmp[0] = __float2bfloat16(sc.x * ((float)c4.x - zp.x));
        tmp[1] = __float2bfloat16(sc.y * ((float)c4.y - zp.y));
        tmp[2] = __float2bfloat16(sc.z * ((float)c4.z - zp.z));
        tmp[3] = __float2bfloat16(sc.w * ((float)c4.w - zp.w));
        *(uint2*)&sK[r * 132 + col] = *(const uint2*)tmp;
        *(uint2*)(kco + idx * 4)    = *(const uint2*)tmp;
    }
    __syncthreads();

    short8 af[4];
#pragma unroll
    for (int ks = 0; ks < 4; ++ks)
        af[ks] = *(const short8*)&sK[(w * 16 + li) * 132 + ks * 32 + quad * 8];
    float s4[4] = {0.f, 0.f, 0.f, 0.f};
#pragma unroll
    for (int nt = 0; nt < 8; ++nt) {
        floatx4 a0 = (floatx4){0.f, 0.f, 0.f, 0.f};
#pragma unroll
        for (int ks = 0; ks < 4; ++ks) {
            short8 bf = *(const short8*)(G + (size_t)(nt * 16 + li) * DC + ks * 32 + quad * 8);
            a0 = mfma16(af[ks], bf, a0);
        }
        int c2 = nt * 16 + li;
#pragma unroll
        for (int r = 0; r < 4; ++r)
            s4[r] += a0[r] * __bfloat162float(sK[(w * 16 + quad * 4 + r) * 132 + c2]);
    }
#pragma unroll
    for (int r = 0; r < 4; ++r) {
        float v = s4[r];
        v += __shfl_xor(v, 1); v += __shfl_xor(v, 2);
        v += __shfl_xor(v, 4); v += __shfl_xor(v, 8);
        if (li == 0)
            k_sq[(size_t)b * LK + l0 + w * 16 + quad * 4 + r] = v;
    }
}

// ---------------------------------------------------------------------------
// K4: main. REBUILT around concurrency: global_load_lds staging (no staging
// VGPRs/VALU), linear LDS + both-sides XOR swizzle (src chunk ^= row&7,
// read chunk ^= row&7 — bijective involution, bank-equivalent to padded),
// __launch_bounds__(256,4) -> 4 blocks/CU (was 3, VGPR-capped), 3 barriers
// per block (was ~7), R1-style direct nontemporal-float4 epilogue (no LDS).
__global__ __launch_bounds__(256, 4) void k_main(const __hip_bfloat16* __restrict__ qproj,
                                                 const __hip_bfloat16* __restrict__ kc,
                                                 const float* __restrict__ q_sq,
                                                 const float* __restrict__ k_sq,
                                                 float* __restrict__ out) {
    __shared__ __hip_bfloat16 sA[128 * 64];   // 16 KB, current k-half of qproj tile
    __shared__ __hip_bfloat16 sB[128 * 64];   // 16 KB, current k-half of kc tile
    int t = threadIdx.x, lane = t & 63, w = t >> 6;
    int quad = lane >> 4, li = lane & 15;
    int wm = w >> 1, wn = w & 1;
    int bid = blockIdx.x;
    int b   = bid & 7;                 // XCD-pinned batch (harmless, kept)
    int rem = bid >> 3;
    int m0  = (rem & 7) << 7;
    int n0  = (rem >> 3) << 7;
    const char* Ag = (const char*)(qproj + ((size_t)b * LQ + m0) * DC);  // 256 B rows
    const char* Bg = (const char*)(kc   + ((size_t)b * LK + n0) * DC);

    int lrow = lane >> 3;              // 0..7: row within the wave's 8-row group
    int lch  = (lane & 7) ^ lrow;      // pre-swizzled source chunk (16 B units)

    floatx4 acc[4][4];   // [i: m-frag][j: n-frag]; reg r = n-local (quad*4+r)
#pragma unroll
    for (int i = 0; i < 4; ++i)
#pragma unroll
        for (int j = 0; j < 4; ++j)
            acc[i][j] = (floatx4){0.f, 0.f, 0.f, 0.f};

#pragma unroll
    for (int h = 0; h < 2; ++h) {
        // stage half h: each wave DMAs 4x 1KB contiguous LDS spans (A and B).
        // LDS slot (row, ch) receives global chunk ch ^ (row&7).
#pragma unroll
        for (int it = 0; it < 4; ++it) {
            int rbase = it * 32 + w * 8;                       // wave-uniform
            size_t goff = (size_t)(rbase + lrow) * 256 + (size_t)(h * 8 + lch) * 16;
            gl16(Ag + goff, (char*)sA + rbase * 128);
            gl16(Bg + goff, (char*)sB + rbase * 128);
        }
        __syncthreads();   // compiler drains vmcnt(0) before s_barrier
#pragma unroll
        for (int ks = 0; ks < 2; ++ks) {
            int ac = ((ks * 4 + quad) ^ (li & 7)) * 16;        // swizzled read
            short8 qf[4], kf[4];
#pragma unroll
            for (int i = 0; i < 4; ++i) {
                qf[i] = *(const short8*)((const char*)sA + (wm * 64 + i * 16 + li) * 128 + ac);
                kf[i] = *(const short8*)((const char*)sB + (wn * 64 + i * 16 + li) * 128 + ac);
            }
#pragma unroll
            for (int i = 0; i < 4; ++i)
#pragma unroll
                for (int j = 0; j < 4; ++j)
                    acc[i][j] = mfma16(kf[j], qf[i], acc[i][j]);   // A=kc, B=qproj
        }
        if (h == 0) __syncthreads();   // protect sA/sB before h=1 overwrite
    }

    // epilogue (R1): k_sq float4, direct nontemporal float4 stores.
    floatx4 ks4[4], kn4[4];
#pragma unroll
    for (int j = 0; j < 4; ++j) {
        ks4[j] = *(const floatx4*)(k_sq + (size_t)b * LK + n0 + wn * 64 + j * 16 + quad * 4);
#pragma unroll
        for (int r = 0; r < 4; ++r)
            kn4[j][r] = 1.f - fminf(ks4[j][r], 1.f - EPSF);
    }
#pragma unroll
    for (int i = 0; i < 4; ++i) {
        int m = m0 + wm * 64 + i * 16 + li;
        float qs  = q_sq[(size_t)b * LQ + m];
        float omq = 1.f - fminf(qs, 1.f - EPSF);
        float* orow = out + ((size_t)b * LQ + m) * (size_t)LK + n0 + wn * 64;
#pragma unroll
        for (int j = 0; j < 4; ++j) {
            floatx4 o;
#pragma unroll
            for (int r = 0; r < 4; ++r) {
                float diff  = fmaxf(qs + ks4[j][r] - 2.f * acc[i][j][r], 0.f);
                float delta = 2.f * diff * fast_rcp(omq * kn4[j][r] + EPSF);
                float sq    = fast_sqrt(delta * (delta + 2.f));
                o[r] = fast_ln(1.f + delta + sq);
            }
            __builtin_nontemporal_store(o, (floatx4*)(orow + j * 16 + quad * 4));
        }
    }
}

// ---------------------------------------------------------------------------
extern "C" void kernel_launch(void* const* d_in, const int* in_sizes, int n_in,
                              void* d_out, int out_size, void* d_ws, size_t ws_size,
                              hipStream_t stream) {
    const float* q      = (const float*)d_in[0];
    const int*   kq     = (const int*)d_in[1];
    const float* kscale = (const float*)d_in[2];
    const float* kzero  = (const float*)d_in[3];
    const float* W      = (const float*)d_in[4];
    float* out = (float*)d_out;

    // workspace layout (19.2 MB total, unchanged)
    char* ws = (char*)d_ws;
    __hip_bfloat16* qproj = (__hip_bfloat16*)(ws);                 // 2,097,152 B
    __hip_bfloat16* kc    = (__hip_bfloat16*)(ws + 2097152);       // 16,777,216 B
    __hip_bfloat16* G     = (__hip_bfloat16*)(ws + 18874368);      //    32,768 B
    float*          q_sq  = (float*)(ws + 18907136);               //    32,768 B
    float*          k_sq  = (float*)(ws + 18939904);               //   262,144 B
    __hip_bfloat16* Wt    = kc;   // 64 KB scratch: k_G writes, k_qproj reads,
                                  // k_dq_ksq overwrites (stream-ordered).

    k_G     <<<128, 512, 0, stream>>>(W, G, Wt);
    k_qproj <<<256, 256, 0, stream>>>(q, Wt, qproj, q_sq);
    k_dq_ksq<<<1024, 256, 0, stream>>>(kq, kscale, kzero, G, kc, k_sq);
    k_main  <<<4096, 256, 0, stream>>>(qproj, kc, q_sq, k_sq, out);
}